// Round 7
// baseline (1901.363 us; speedup 1.0000x reference)
//
#include <hip/hip_runtime.h>

typedef unsigned short u16;
typedef unsigned int u32;
typedef unsigned long long u64;
typedef short v8s __attribute__((ext_vector_type(8)));
typedef float v4f __attribute__((ext_vector_type(4)));

#define NN 4096
#define BATCH 32

__device__ __forceinline__ float b2f(u16 u) {
  union { u32 i; float f; } c; c.i = ((u32)u) << 16; return c.f;
}
__device__ __forceinline__ u16 f2b(float f) {
  union { float f; u32 i; } c; c.f = f;
  u32 x = c.i;
  return (u16)((x + 0x7fffu + ((x >> 16) & 1u)) >> 16);
}
__device__ __forceinline__ u32 pk2(float a, float b) {
  return (u32)f2b(a) | ((u32)f2b(b) << 16);
}

typedef const __attribute__((address_space(1))) u32* gp_t;
typedef __attribute__((address_space(3))) u32* lp_t;
__device__ __forceinline__ void gld16(const u16* g, u16* l) {
  __builtin_amdgcn_global_load_lds((gp_t)g, (lp_t)l, 16, 0, 0);
}

#define CBAR() asm volatile("" ::: "memory")
#define BARRIER() do { CBAR(); __builtin_amdgcn_s_barrier(); CBAR(); } while (0)
#define LGKM0() asm volatile("s_waitcnt lgkmcnt(0)" ::: "memory")
#define VMC2() asm volatile("s_waitcnt vmcnt(2)" ::: "memory")
#define VMC0() asm volatile("s_waitcnt vmcnt(0)" ::: "memory")

// ---------------------------------------------------------------------------
// cvtS: f32 -> bf16 (RNE), 8 elems/thread. grid: 8192 x 256 for 16.8M elems.
// ---------------------------------------------------------------------------
__global__ __launch_bounds__(256) void cvtS(const float* __restrict__ S,
                                            u16* __restrict__ Sb) {
  const u64 idx = ((u64)blockIdx.x * 256 + threadIdx.x) * 8;
  const float4 a = *(const float4*)(S + idx);
  const float4 b = *(const float4*)(S + idx + 4);
  uint4 o;
  o.x = pk2(a.x, a.y); o.y = pk2(a.z, a.w);
  o.z = pk2(b.x, b.y); o.w = pk2(b.z, b.w);
  *(uint4*)(Sb + idx) = o;
}

// ---------------------------------------------------------------------------
// gemm256 (v7): 256x256 tile, BK=64, 16 waves (4Mx4N) in a 1024-thread block.
// Per-wave 64x64 output (acc[4][4] = 64 regs; <=128 VGPR -> 4 waves/SIMD).
// Same swizzled double-buffered 128KB LDS and hazard structure as before;
// 2 K-half phases per tile, 2 barriers, per-wave vmcnt(2) leaves B(T+2)'s
// 2 staging ops in flight. 4 independent waves/SIMD cover ds-read latency
// and drain stalls that 2 waves could not. grid (16, C/256), block 1024.
// ---------------------------------------------------------------------------
__global__ __launch_bounds__(1024, 4) void gemm256(const u16* __restrict__ A,
                                                   const u16* __restrict__ B,
                                                   u16* __restrict__ Ct,
                                                   const u16* __restrict__ Xt) {
  // buf b at b*32768 u16: A [256][64] at 0 | B [256][64] at 16384
  __shared__ __align__(16) u16 lds[65536];
  const int t = threadIdx.x;
  const int wave = t >> 6, lane = t & 63;
  const int q = lane >> 4, r16 = lane & 15;
  const int wm = wave >> 2, wn = wave & 3;   // 4x4 wave grid

  const int nwg = (int)(gridDim.x * gridDim.y);
  const int bid = (int)(blockIdx.y * gridDim.x + blockIdx.x);
  const int swz = (bid & 7) * (nwg >> 3) + (bid >> 3);
  const int m0 = (swz & 15) << 8;   // gridDim.x == 16 always
  const int c0 = (swz >> 4) << 8;

  v4f acc[4][4];
  const v4f vz = {0.f, 0.f, 0.f, 0.f};
#pragma unroll
  for (int i = 0; i < 4; ++i)
#pragma unroll
    for (int j = 0; j < 4; ++j) acc[i][j] = vz;

  // staging: thread t covers row (t>>3) (0..127), 16B slot (t&7);
  // source col pre-swizzled by row&7 so swizzled ds_reads see linear data
  const int srow = t >> 3;
  const int sslot = ((t & 7) ^ (srow & 7)) << 3;
  const u16* pA = A + (u64)(m0 + srow) * NN + sslot;
  const u16* pB = B + (u64)(c0 + srow) * NN + sslot;
  const u64 rstep = (u64)128 * NN;            // second stage-op row offset
  u16* lw = lds + (wave << 9);                // wave-uniform LDS dest

  const int sw8 = (q ^ (r16 & 7)) << 3;
  const int aBase = (wm << 12) + (r16 << 6) + sw8;           // + i<<10
  const int bBase = 16384 + (wn << 12) + (r16 << 6) + sw8;   // + j<<10

  const int NT = NN >> 6;  // 64 K-tiles

  // prologue: A(0) 2 ops, B(0) 2 ops, B(1) 2 ops; VMC2 leaves B(1) in flight
  gld16(pA, lw);
  gld16(pA + rstep, lw + 8192);
  gld16(pB, lw + 16384);
  gld16(pB + rstep, lw + 24576);
  gld16(pB + 64, lw + 32768 + 16384);
  gld16(pB + 64 + rstep, lw + 32768 + 24576);
  VMC2();
  BARRIER();

#pragma unroll 2
  for (int T = 0; T < NT; ++T) {
    const int bo = (T & 1) << 15;
    const int no = bo ^ 32768;
    const u64 ka = (u64)(T + 1 < NT ? T + 1 : NT - 1) << 6;
    const u64 kb = (u64)(T + 2 < NT ? T + 2 : NT - 1) << 6;

    // ---- P0: stage A(T+1) | read K-half0 | MFMA 16
    gld16(pA + ka, lw + no);
    gld16(pA + ka + rstep, lw + no + 8192);
    {
      v8s af[4], bf[4];
#pragma unroll
      for (int i = 0; i < 4; ++i) af[i] = *(const v8s*)(lds + bo + aBase + (i << 10));
#pragma unroll
      for (int j = 0; j < 4; ++j) bf[j] = *(const v8s*)(lds + bo + bBase + (j << 10));
      __builtin_amdgcn_s_setprio(1);
#pragma unroll
      for (int i = 0; i < 4; ++i)
#pragma unroll
        for (int j = 0; j < 4; ++j)
          acc[i][j] = __builtin_amdgcn_mfma_f32_16x16x32_bf16(af[i], bf[j], acc[i][j], 0, 0, 0);
      __builtin_amdgcn_s_setprio(0);
    }

    // ---- P1: read K-half1 | lgkm-drain + BARRIER (B-region WAR) |
    //          stage B(T+2) | MFMA 16 | vmcnt(2) + BARRIER
    {
      v8s ag[4], bg[4];
#pragma unroll
      for (int i = 0; i < 4; ++i) ag[i] = *(const v8s*)(lds + ((bo + aBase + (i << 10)) ^ 32));
#pragma unroll
      for (int j = 0; j < 4; ++j) bg[j] = *(const v8s*)(lds + ((bo + bBase + (j << 10)) ^ 32));
      LGKM0();     // all this wave's bo reads architecturally complete
      BARRIER();   // every wave's reads done before B(T+2) staging below
      gld16(pB + kb, lw + bo + 16384);
      gld16(pB + kb + rstep, lw + bo + 24576);
      __builtin_amdgcn_s_setprio(1);
#pragma unroll
      for (int i = 0; i < 4; ++i)
#pragma unroll
        for (int j = 0; j < 4; ++j)
          acc[i][j] = __builtin_amdgcn_mfma_f32_16x16x32_bf16(ag[i], bg[j], acc[i][j], 0, 0, 0);
      __builtin_amdgcn_s_setprio(0);
    }
    VMC2();   // A(T+1)+B(T+1) landed; only B(T+2)'s 2 ops stay in flight
    BARRIER();
  }

  // ---------------- epilogue: 256c x 256m C-tile through LDS ----------------
  VMC0();
  __syncthreads();
#pragma unroll
  for (int i = 0; i < 4; ++i)
#pragma unroll
    for (int j = 0; j < 4; ++j) {
      const int cl = (wn << 6) + (j << 4) + r16;
      const int ml = (wm << 6) + (i << 4) + (q << 2);
      const int phys = (cl << 8) + ((((ml >> 3) ^ (cl & 7)) << 3) | (ml & 7));
      uint2 pv;
      pv.x = pk2(acc[i][j][0], acc[i][j][1]);
      pv.y = pk2(acc[i][j][2], acc[i][j][3]);
      *(uint2*)(lds + phys) = pv;
    }
  __syncthreads();
#pragma unroll
  for (int it = 0; it < 8; ++it) {
    const int f = (it << 10) + t;
    const int cl = f >> 5, sl = f & 31;
    const int phys = (cl << 8) + ((sl ^ (cl & 7)) << 3);
    union { uint4 v; u16 e[8]; } tv;
    tv.v = *(const uint4*)(lds + phys);
    const u64 gi = (u64)(c0 + cl) * NN + m0 + (sl << 3);
    if (Xt) {
      union { uint4 v; u16 e[8]; } xv, ov;
      xv.v = *(const uint4*)(Xt + gi);
#pragma unroll
      for (int s = 0; s < 8; ++s) ov.e[s] = f2b(2.f * b2f(tv.e[s]) - b2f(xv.e[s]));
      *(uint4*)(Ct + gi) = ov.v;
    } else {
      *(uint4*)(Ct + gi) = tv.v;
    }
  }
}

// ---------------------------------------------------------------------------
// gemm192 (v7): 256x192 tile, BK=64, 16 waves (4Mx4N, per-wave 64x48,
// acc[4][3]). Identical schedule/hazards to gemm256 v7. B region padded to
// 32KB (rows 192..255 slack, staged but never read) so both staging ops are
// full-width and vmcnt is wave-uniform. grid (16, 12), block 1024.
// ---------------------------------------------------------------------------
__global__ __launch_bounds__(1024, 4) void gemm192(const u16* __restrict__ A,
                                                   const u16* __restrict__ B,
                                                   u16* __restrict__ Ct,
                                                   const u16* __restrict__ Xt) {
  __shared__ __align__(16) u16 lds[65536];
  const int t = threadIdx.x;
  const int wave = t >> 6, lane = t & 63;
  const int q = lane >> 4, r16 = lane & 15;
  const int wm = wave >> 2, wn = wave & 3;

  const int nwg = (int)(gridDim.x * gridDim.y);   // 192
  const int bid = (int)(blockIdx.y * gridDim.x + blockIdx.x);
  const int swz = (bid & 7) * (nwg >> 3) + (bid >> 3);
  const int m0 = (swz & 15) << 8;                 // gridDim.x == 16
  const int c0 = (swz >> 4) * 192;

  v4f acc[4][3];
  const v4f vz = {0.f, 0.f, 0.f, 0.f};
#pragma unroll
  for (int i = 0; i < 4; ++i)
#pragma unroll
    for (int j = 0; j < 3; ++j) acc[i][j] = vz;

  const int srow = t >> 3;
  const int sslot = ((t & 7) ^ (srow & 7)) << 3;
  const u16* pA = A + (u64)(m0 + srow) * NN + sslot;
  const u16* pB = B + (u64)(c0 + srow) * NN + sslot;
  const u64 rstep = (u64)128 * NN;
  u16* lw = lds + (wave << 9);

  const int sw8 = (q ^ (r16 & 7)) << 3;
  const int aBase = (wm << 12) + (r16 << 6) + sw8;
  const int bBase = 16384 + wn * 3072 + (r16 << 6) + sw8;   // wn*48 rows

  const int NT = NN >> 6;

  gld16(pA, lw);
  gld16(pA + rstep, lw + 8192);
  gld16(pB, lw + 16384);
  gld16(pB + rstep, lw + 24576);
  gld16(pB + 64, lw + 32768 + 16384);
  gld16(pB + 64 + rstep, lw + 32768 + 24576);
  VMC2();
  BARRIER();

#pragma unroll 2
  for (int T = 0; T < NT; ++T) {
    const int bo = (T & 1) << 15;
    const int no = bo ^ 32768;
    const u64 ka = (u64)(T + 1 < NT ? T + 1 : NT - 1) << 6;
    const u64 kb = (u64)(T + 2 < NT ? T + 2 : NT - 1) << 6;

    // ---- P0
    gld16(pA + ka, lw + no);
    gld16(pA + ka + rstep, lw + no + 8192);
    {
      v8s af[4], bf[3];
#pragma unroll
      for (int i = 0; i < 4; ++i) af[i] = *(const v8s*)(lds + bo + aBase + (i << 10));
#pragma unroll
      for (int j = 0; j < 3; ++j) bf[j] = *(const v8s*)(lds + bo + bBase + (j << 10));
      __builtin_amdgcn_s_setprio(1);
#pragma unroll
      for (int i = 0; i < 4; ++i)
#pragma unroll
        for (int j = 0; j < 3; ++j)
          acc[i][j] = __builtin_amdgcn_mfma_f32_16x16x32_bf16(af[i], bf[j], acc[i][j], 0, 0, 0);
      __builtin_amdgcn_s_setprio(0);
    }

    // ---- P1
    {
      v8s ag[4], bg[3];
#pragma unroll
      for (int i = 0; i < 4; ++i) ag[i] = *(const v8s*)(lds + ((bo + aBase + (i << 10)) ^ 32));
#pragma unroll
      for (int j = 0; j < 3; ++j) bg[j] = *(const v8s*)(lds + ((bo + bBase + (j << 10)) ^ 32));
      LGKM0();
      BARRIER();
      gld16(pB + kb, lw + bo + 16384);
      gld16(pB + kb + rstep, lw + bo + 24576);
      __builtin_amdgcn_s_setprio(1);
#pragma unroll
      for (int i = 0; i < 4; ++i)
#pragma unroll
        for (int j = 0; j < 3; ++j)
          acc[i][j] = __builtin_amdgcn_mfma_f32_16x16x32_bf16(ag[i], bg[j], acc[i][j], 0, 0, 0);
      __builtin_amdgcn_s_setprio(0);
    }
    VMC2();
    BARRIER();
  }

  // ---------------- epilogue: 192c x 256m through LDS ----------------
  VMC0();
  __syncthreads();
#pragma unroll
  for (int i = 0; i < 4; ++i)
#pragma unroll
    for (int j = 0; j < 3; ++j) {
      const int cl = wn * 48 + (j << 4) + r16;               // 0..191
      const int ml = (wm << 6) + (i << 4) + (q << 2);        // 0..255
      const int phys = (cl << 8) + ((((ml >> 3) ^ (cl & 7)) << 3) | (ml & 7));
      uint2 pv;
      pv.x = pk2(acc[i][j][0], acc[i][j][1]);
      pv.y = pk2(acc[i][j][2], acc[i][j][3]);
      *(uint2*)(lds + phys) = pv;
    }
  __syncthreads();
#pragma unroll
  for (int it = 0; it < 6; ++it) {
    const int f = (it << 10) + t;
    const int cl = f >> 5, sl = f & 31;
    const int phys = (cl << 8) + ((sl ^ (cl & 7)) << 3);
    union { uint4 v; u16 e[8]; } tv;
    tv.v = *(const uint4*)(lds + phys);
    const u64 gi = (u64)(c0 + cl) * NN + m0 + (sl << 3);
    if (Xt) {
      union { uint4 v; u16 e[8]; } xv, ov;
      xv.v = *(const uint4*)(Xt + gi);
#pragma unroll
      for (int s = 0; s < 8; ++s) ov.e[s] = f2b(2.f * b2f(tv.e[s]) - b2f(xv.e[s]));
      *(uint4*)(Ct + gi) = ov.v;
    } else {
      *(uint4*)(Ct + gi) = tv.v;
    }
  }
}

// ---------------------------------------------------------------------------
// gemm_s (fallback if workspace too small for bf16 S): A f32, in-loop cvt.
// ---------------------------------------------------------------------------
__global__ __launch_bounds__(256) void gemm_s(const float* __restrict__ A,
                                              const u16* __restrict__ B,
                                              u16* __restrict__ Ct,
                                              const u16* __restrict__ Xt) {
  __shared__ __align__(16) u16 As[4096];
  __shared__ __align__(16) u16 Bs[4096];
  __shared__ __align__(16) u16 T[16384];
  const int t = threadIdx.x;
  const int wave = t >> 6, lane = t & 63;
  const int m0 = blockIdx.x << 7, c0 = blockIdx.y << 7;
  const int wm = (wave >> 1) << 6, wc = (wave & 1) << 6;
  const int q = lane >> 4, r16 = lane & 15;
  v4f acc[4][4];
  const v4f vz = {0.f, 0.f, 0.f, 0.f};
#pragma unroll
  for (int i = 0; i < 4; ++i)
#pragma unroll
    for (int j = 0; j < 4; ++j) acc[i][j] = vz;

  const int sr = t >> 2;
  const int sc = (t & 3) << 3;
  const u64 abase = (u64)(m0 + sr) * NN + sc;
  const u64 bbase = (u64)(c0 + sr) * NN + sc;
  const u64 rstep = (u64)64 * NN;
  u16* as0 = As + sr * 32 + sc;
  u16* as1 = As + (64 + sr) * 32 + sc;
  u16* bs0 = Bs + sr * 32 + sc;
  u16* bs1 = Bs + (64 + sr) * 32 + sc;

  for (int k0 = 0; k0 < NN; k0 += 32) {
    const float4 a0l = *(const float4*)(A + abase + k0);
    const float4 a0h = *(const float4*)(A + abase + k0 + 4);
    const float4 a1l = *(const float4*)(A + abase + rstep + k0);
    const float4 a1h = *(const float4*)(A + abase + rstep + k0 + 4);
    const uint4 b0 = *(const uint4*)(B + bbase + k0);
    const uint4 b1 = *(const uint4*)(B + bbase + rstep + k0);
    uint4 pa0, pa1;
    pa0.x = pk2(a0l.x, a0l.y); pa0.y = pk2(a0l.z, a0l.w);
    pa0.z = pk2(a0h.x, a0h.y); pa0.w = pk2(a0h.z, a0h.w);
    pa1.x = pk2(a1l.x, a1l.y); pa1.y = pk2(a1l.z, a1l.w);
    pa1.z = pk2(a1h.x, a1h.y); pa1.w = pk2(a1h.z, a1h.w);
    __syncthreads();
    *(uint4*)as0 = pa0;
    *(uint4*)as1 = pa1;
    *(uint4*)bs0 = b0;
    *(uint4*)bs1 = b1;
    __syncthreads();
    v8s af[4], bf[4];
#pragma unroll
    for (int i = 0; i < 4; ++i)
      af[i] = *(const v8s*)(As + ((wm + i * 16 + r16) << 5) + (q << 3));
#pragma unroll
    for (int j = 0; j < 4; ++j)
      bf[j] = *(const v8s*)(Bs + ((wc + j * 16 + r16) << 5) + (q << 3));
#pragma unroll
    for (int i = 0; i < 4; ++i)
#pragma unroll
      for (int j = 0; j < 4; ++j)
        acc[i][j] = __builtin_amdgcn_mfma_f32_16x16x32_bf16(af[i], bf[j], acc[i][j], 0, 0, 0);
  }
#pragma unroll
  for (int i = 0; i < 4; ++i)
#pragma unroll
    for (int j = 0; j < 4; ++j) {
      const int cl = wc + j * 16 + r16;
      const int mm = wm + i * 16 + (q << 2);
      uint2 pv;
      pv.x = pk2(acc[i][j][0], acc[i][j][1]);
      pv.y = pk2(acc[i][j][2], acc[i][j][3]);
      *(uint2*)(T + (cl << 7) + mm) = pv;
    }
  __syncthreads();
#pragma unroll
  for (int it = 0; it < 8; ++it) {
    const int flat = it * 256 + t;
    const int cl = flat >> 4;
    const int seg = (flat & 15) << 3;
    const u64 gi = (u64)(c0 + cl) * NN + m0 + seg;
    union { uint4 v; u16 e[8]; } tv;
    tv.v = *(uint4*)(T + (cl << 7) + seg);
    if (Xt) {
      union { uint4 v; u16 e[8]; } xv, ov;
      xv.v = *(const uint4*)(Xt + gi);
#pragma unroll
      for (int s = 0; s < 8; ++s) ov.e[s] = f2b(2.f * b2f(tv.e[s]) - b2f(xv.e[s]));
      *(uint4*)(Ct + gi) = ov.v;
    } else {
      *(uint4*)(Ct + gi) = tv.v;
    }
  }
}

// ---------------------------------------------------------------------------
// Projection: out[b*JSTR + j][n] = act( sum_k Wt[j][k] * F[row(k,b)][n] + b[j] )
// ---------------------------------------------------------------------------
template <int DP, int KTOT>
__global__ __launch_bounds__(256) void proj_k(const u16* __restrict__ Wt,
                                              const u16* __restrict__ F,
                                              const float* __restrict__ bias,
                                              u16* __restrict__ outp,
                                              const int JSTR, const int ACT) {
  __shared__ __align__(16) u16 As2[2048];  // 64 j x 32 k
  __shared__ __align__(16) u16 Bs2[4096];  // 32 k x 128 n
  const int t = threadIdx.x;
  const int wave = t >> 6, lane = t & 63;
  const int q = lane >> 4, r16 = lane & 15;
  const int n0 = blockIdx.x << 7;
  const int j0 = blockIdx.y << 6;
  const int b = blockIdx.z;
  v4f acc[4][2];
  const v4f vz = {0.f, 0.f, 0.f, 0.f};
#pragma unroll
  for (int i = 0; i < 4; ++i) { acc[i][0] = vz; acc[i][1] = vz; }

  const int ar = t >> 2, ac = (t & 3) << 3;
  const u64 wbase = (u64)(j0 + ar) * KTOT + ac;

  for (int k0 = 0; k0 < KTOT; k0 += 32) {
    const uint4 av = *(const uint4*)(Wt + wbase + k0);
    uint4 bv[2];
#pragma unroll
    for (int ci = 0; ci < 2; ++ci) {
      const int c = ci * 256 + t;
      const int kr = c >> 4;
      const int seg = (c & 15) << 3;
      const int kk = k0 + kr;
      const int i = kk / DP;
      const int d = kk - i * DP;
      bv[ci] = *(const uint4*)(F + ((u64)i * (BATCH * DP) + (u64)b * DP + d) * NN + n0 + seg);
    }
    __syncthreads();
    *(uint4*)(As2 + ar * 32 + ac) = av;
#pragma unroll
    for (int ci = 0; ci < 2; ++ci) {
      const int c = ci * 256 + t;
      const int kr = c >> 4;
      const int seg = (c & 15) << 3;
      *(uint4*)(Bs2 + (kr << 7) + seg) = bv[ci];
    }
    __syncthreads();
    v8s af[4], bf[2];
#pragma unroll
    for (int i = 0; i < 4; ++i)
      af[i] = *(const v8s*)(As2 + ((i * 16 + r16) << 5) + (q << 3));
#pragma unroll
    for (int jj = 0; jj < 2; ++jj) {
      const int nn = (wave << 5) + jj * 16 + r16;
      v8s v;
#pragma unroll
      for (int s = 0; s < 8; ++s) v[s] = (short)Bs2[(((q << 3) + s) << 7) + nn];
      bf[jj] = v;
    }
#pragma unroll
    for (int i = 0; i < 4; ++i)
#pragma unroll
      for (int jj = 0; jj < 2; ++jj)
        acc[i][jj] = __builtin_amdgcn_mfma_f32_16x16x32_bf16(af[i], bf[jj], acc[i][jj], 0, 0, 0);
  }
#pragma unroll
  for (int i = 0; i < 4; ++i)
#pragma unroll
    for (int jj = 0; jj < 2; ++jj)
#pragma unroll
      for (int r = 0; r < 4; ++r) {
        const int j = j0 + i * 16 + (q << 2) + r;
        const int n = n0 + (wave << 5) + jj * 16 + r16;
        float v = acc[i][jj][r] + bias[j];
        v = ACT ? (1.f - 2.f / (__expf(2.f * v) + 1.f)) : (1.f / (1.f + __expf(-v)));
        outp[((u64)b * JSTR + j) * NN + n] = f2b(v);
      }
}

// ---------------------------------------------------------------------------
__global__ __launch_bounds__(256) void repackW(const float* __restrict__ W, u16* __restrict__ Wt,
                                               const int D, const int DP, const int KTOT,
                                               const int J) {
  const int idx = blockIdx.x * 256 + threadIdx.x;
  if (idx >= J * KTOT) return;
  const int j = idx / KTOT, k = idx - j * KTOT;
  const int i = k / DP, d = k - i * DP;
  u16 v = 0;
  if (i < 5 && d < D) v = f2b(W[(i * D + d) * J + j]);
  Wt[idx] = v;
}

// ---------------------------------------------------------------------------
__global__ __launch_bounds__(256) void pack0(const float* __restrict__ x,
                                             const float* __restrict__ hid0,
                                             u16* __restrict__ F0) {
  __shared__ __align__(16) u16 Hs[64 * 72];
  const int b = blockIdx.y, n0 = blockIdx.x << 6, t = threadIdx.x;
  const int r = t >> 2, ds = t & 3;
  const float* hrow = hid0 + ((u64)b * NN + n0 + r) * 64;
#pragma unroll
  for (int c4 = 0; c4 < 4; ++c4) {
    const float4 v = *(const float4*)(hrow + ds * 16 + c4 * 4);
    uint2 p;
    p.x = pk2(v.x, v.y);
    p.y = pk2(v.z, v.w);
    *(uint2*)(Hs + r * 72 + ds * 16 + c4 * 4) = p;
  }
  __syncthreads();
#pragma unroll
  for (int c2 = 0; c2 < 2; ++c2) {
    union { uint4 v; u16 h[8]; } o;
#pragma unroll
    for (int s = 0; s < 8; ++s) o.h[s] = Hs[(ds * 16 + c2 * 8 + s) * 72 + r];
    *(uint4*)(F0 + ((u64)b * 72 + 1 + r) * NN + n0 + ds * 16 + c2 * 8) = o.v;
  }
  if (t < 64) {
    F0[(u64)b * 72 * NN + n0 + t] = f2b(x[(u64)b * NN + n0 + t]);
  } else if (t < 120) {
    const int tt = t - 64;
    const int row = 65 + (tt >> 3), seg = (tt & 7) << 3;
    uint4 z; z.x = z.y = z.z = z.w = 0;
    *(uint4*)(F0 + ((u64)b * 72 + row) * NN + n0 + seg) = z;
  }
}

// ---------------------------------------------------------------------------
__global__ __launch_bounds__(256) void pack1(const float* __restrict__ hid1,
                                             u16* __restrict__ F1) {
  __shared__ __align__(16) u16 Hs[64 * 72];
  const int b = blockIdx.y, n0 = blockIdx.x << 6, t = threadIdx.x;
  const int r = t >> 2, ds = t & 3;
  const float* hrow = hid1 + ((u64)b * NN + n0 + r) * 64;
#pragma unroll
  for (int c4 = 0; c4 < 4; ++c4) {
    const float4 v = *(const float4*)(hrow + ds * 16 + c4 * 4);
    uint2 p;
    p.x = pk2(v.x, v.y);
    p.y = pk2(v.z, v.w);
    *(uint2*)(Hs + r * 72 + ds * 16 + c4 * 4) = p;
  }
  __syncthreads();
#pragma unroll
  for (int c2 = 0; c2 < 2; ++c2) {
    union { uint4 v; u16 h[8]; } o;
#pragma unroll
    for (int s = 0; s < 8; ++s) o.h[s] = Hs[(ds * 16 + c2 * 8 + s) * 72 + r];
    *(uint4*)(F1 + ((u64)b * 128 + 64 + r) * NN + n0 + ds * 16 + c2 * 8) = o.v;
  }
}

// ---------------------------------------------------------------------------
__global__ __launch_bounds__(256) void candpack(const u16* __restrict__ G, u16* __restrict__ F,
                                                const int DP, const int OFF) {
  const int u = blockIdx.x * 256 + threadIdx.x;
  const int b = u >> 15;
  const int d = (u >> 9) & 63;
  const int seg = (u & 511) << 3;
  union { uint4 v; u16 h[8]; } g, f, o;
  g.v = *(const uint4*)(G + ((u64)b * 128 + d) * NN + seg);
  u16* fp = F + ((u64)b * DP + OFF + d) * NN + seg;
  f.v = *(const uint4*)fp;
#pragma unroll
  for (int s = 0; s < 8; ++s) o.h[s] = f2b(b2f(f.h[s]) * b2f(g.h[s]));
  *(uint4*)fp = o.v;
}

// ---------------------------------------------------------------------------
__global__ __launch_bounds__(256) void hnew_k(const u16* __restrict__ G,
                                              const float* __restrict__ hidL,
                                              u16* __restrict__ HnF,
                                              float* __restrict__ outH) {
  __shared__ __align__(16) float Hs[64 * 72];
  __shared__ __align__(16) float T2[64 * 72];
  const int b = blockIdx.y, n0 = blockIdx.x << 6, t = threadIdx.x;
  const int r = t >> 2, ds = t & 3;
  const float* hrow = hidL + ((u64)b * NN + n0 + r) * 64;
#pragma unroll
  for (int c4 = 0; c4 < 4; ++c4)
    *(float4*)(Hs + r * 72 + ds * 16 + c4 * 4) = *(const float4*)(hrow + ds * 16 + c4 * 4);
  __syncthreads();
#pragma unroll
  for (int c2 = 0; c2 < 2; ++c2) {
    const int ncol = ds * 16 + c2 * 8;
    union { uint4 v; u16 h[8]; } uv, cv, o;
    uv.v = *(const uint4*)(G + ((u64)b * 128 + 64 + r) * NN + n0 + ncol);
    cv.v = *(const uint4*)(G + ((u64)b * 128 + r) * NN + n0 + ncol);
#pragma unroll
    for (int s = 0; s < 8; ++s) {
      const int nl = ncol + s;
      const float uu = b2f(uv.h[s]);
      const float hh = Hs[nl * 72 + r];
      const float cc = b2f(cv.h[s]);
      const float v = uu * hh + (1.f - uu) * cc;
      o.h[s] = f2b(v);
      T2[nl * 72 + r] = v;
    }
    *(uint4*)(HnF + ((u64)b * 128 + r) * NN + n0 + ncol) = o.v;
  }
  __syncthreads();
  const int nl2 = t >> 2, dseg = (t & 3) << 4;
#pragma unroll
  for (int c4 = 0; c4 < 4; ++c4) {
    const float4 v = *(const float4*)(T2 + nl2 * 72 + dseg + c4 * 4);
    *(float4*)(outH + ((u64)b * NN + n0 + nl2) * 64 + dseg + c4 * 4) = v;
  }
}

// ---------------------------------------------------------------------------
__global__ __launch_bounds__(256) void predictk(const float* __restrict__ H1bnd,
                                                const float* __restrict__ Wp,
                                                const float* __restrict__ bp,
                                                float* __restrict__ outp) {
  __shared__ float w[64];
  __shared__ float bb;
  const int t = threadIdx.x;
  if (t < 64) w[t] = Wp[t];
  if (t == 64) bb = bp[0];
  __syncthreads();
  const int idx = blockIdx.x * 256 + t;
  const float* h = H1bnd + (u64)idx * 64;
  float acc = bb;
#pragma unroll
  for (int c4 = 0; c4 < 16; ++c4) {
    const float4 v = *(const float4*)(h + c4 * 4);
    acc += v.x * w[c4 * 4] + v.y * w[c4 * 4 + 1] + v.z * w[c4 * 4 + 2] + v.w * w[c4 * 4 + 3];
  }
  outp[idx] = acc;
}

extern "C" void kernel_launch(void* const* d_in, const int* in_sizes, int n_in,
                              void* d_out, int out_size, void* d_ws, size_t ws_size,
                              hipStream_t stream) {
  const float* X   = (const float*)d_in[0];
  const float* HID = (const float*)d_in[1];
  const float* Sf  = (const float*)d_in[2];
  const float* Sb  = (const float*)d_in[3];
  const float* Wg0 = (const float*)d_in[4];
  const float* bg0 = (const float*)d_in[5];
  const float* Wc0 = (const float*)d_in[6];
  const float* bc0 = (const float*)d_in[7];
  const float* Wg1 = (const float*)d_in[8];
  const float* bg1 = (const float*)d_in[9];
  const float* Wc1 = (const float*)d_in[10];
  const float* bc1 = (const float*)d_in[11];
  const float* Wp  = (const float*)d_in[12];
  const float* bp  = (const float*)d_in[13];
  float* OUT = (float*)d_out;
  char* ws = (char*)d_ws;

  u16* F = (u16*)(ws);
  u16* G = (u16*)(ws + 167772160ull);
  const u64 NEED_BIG = 167772160ull + 33554432ull + 2ull * 33554432ull + 393216ull;
  const bool big = ws_size >= NEED_BIG;
  u16* Sfb = (u16*)(ws + 167772160ull + 33554432ull);
  u16* Sbb = Sfb + (u64)NN * NN;
  u16* WT = big ? (Sbb + (u64)NN * NN)
                : (u16*)(ws + 167772160ull + 33554432ull);
  u16* Wg0t = WT;                   // 128 x 384
  u16* Wc0t = Wg0t + 128 * 384;     // 64 x 384
  u16* Wg1t = Wc0t + 64 * 384;      // 128 x 640
  u16* Wc1t = Wg1t + 128 * 640;     // 64 x 640

  const float* HID1 = HID + (u64)32 * 4096 * 64;
  float* OUT_H0 = OUT + 131072;
  float* OUT_H1 = OUT + 131072 + 8388608;

  // zero the layer-0 K-padding region of F (rows 11520..13823), read by proj i=5
  hipMemsetAsync(ws + (u64)11520 * NN * 2, 0, (u64)2304 * NN * 2, stream);

  if (big) {
    cvtS<<<8192, 256, 0, stream>>>(Sf, Sfb);
    cvtS<<<8192, 256, 0, stream>>>(Sb, Sbb);
  }

  repackW<<<(128 * 384 + 255) / 256, 256, 0, stream>>>(Wg0, Wg0t, 65, 72, 384, 128);
  repackW<<<(64 * 384 + 255) / 256, 256, 0, stream>>>(Wc0, Wc0t, 65, 72, 384, 64);
  repackW<<<(128 * 640 + 255) / 256, 256, 0, stream>>>(Wg1, Wg1t, 128, 128, 640, 128);
  repackW<<<(64 * 640 + 255) / 256, 256, 0, stream>>>(Wc1, Wc1t, 128, 128, 640, 64);

  // ---------------- layer 0 (Dp=72, C=2304) ----------------
  pack0<<<dim3(64, 32), 256, 0, stream>>>(X, HID, F);
  const u64 R0 = (u64)2304 * NN;
  const dim3 g192(16, 12);
  if (big) {
    gemm192<<<g192, 1024, 0, stream>>>(Sfb, F, F + R0, nullptr);
    gemm192<<<g192, 1024, 0, stream>>>(Sbb, F, F + 3 * R0, nullptr);
    gemm192<<<g192, 1024, 0, stream>>>(Sfb, F + R0, F + 2 * R0, F);
    gemm192<<<g192, 1024, 0, stream>>>(Sbb, F + 3 * R0, F + 4 * R0, F);
  } else {
    gemm_s<<<dim3(32, 18), 256, 0, stream>>>(Sf, F, F + R0, nullptr);
    gemm_s<<<dim3(32, 18), 256, 0, stream>>>(Sb, F, F + 3 * R0, nullptr);
    gemm_s<<<dim3(32, 18), 256, 0, stream>>>(Sf, F + R0, F + 2 * R0, F);
    gemm_s<<<dim3(32, 18), 256, 0, stream>>>(Sb, F + 3 * R0, F + 4 * R0, F);
  }
  proj_k<72, 384><<<dim3(32, 2, 32), 256, 0, stream>>>(Wg0t, F, bg0, G, 128, 0);
  candpack<<<4096, 256, 0, stream>>>(G, F, 72, 1);
  if (big) {
    gemm192<<<g192, 1024, 0, stream>>>(Sfb, F, F + R0, nullptr);
    gemm192<<<g192, 1024, 0, stream>>>(Sbb, F, F + 3 * R0, nullptr);
    gemm192<<<g192, 1024, 0, stream>>>(Sfb, F + R0, F + 2 * R0, F);
    gemm192<<<g192, 1024, 0, stream>>>(Sbb, F + 3 * R0, F + 4 * R0, F);
  } else {
    gemm_s<<<dim3(32, 18), 256, 0, stream>>>(Sf, F, F + R0, nullptr);
    gemm_s<<<dim3(32, 18), 256, 0, stream>>>(Sb, F, F + 3 * R0, nullptr);
    gemm_s<<<dim3(32, 18), 256, 0, stream>>>(Sf, F + R0, F + 2 * R0, F);
    gemm_s<<<dim3(32, 18), 256, 0, stream>>>(Sb, F + 3 * R0, F + 4 * R0, F);
  }
  proj_k<72, 384><<<dim3(32, 1, 32), 256, 0, stream>>>(Wc0t, F, bc0, G, 128, 1);
  hnew_k<<<dim3(64, 32), 256, 0, stream>>>(G, HID, F, OUT_H0);

  // ---------------- layer 1 (Dp=128, C=4096) ----------------
  pack1<<<dim3(64, 32), 256, 0, stream>>>(HID1, F);
  const u64 R1 = (u64)4096 * NN;
  const dim3 g256(16, 16);
  if (big) {
    gemm256<<<g256, 1024, 0, stream>>>(Sfb, F, F + R1, nullptr);
    gemm256<<<g256, 1024, 0, stream>>>(Sbb, F, F + 3 * R1, nullptr);
    gemm256<<<g256, 1024, 0, stream>>>(Sfb, F + R1, F + 2 * R1, F);
    gemm256<<<g256, 1024, 0, stream>>>(Sbb, F + 3 * R1, F + 4 * R1, F);
  } else {
    gemm_s<<<dim3(32, 32), 256, 0, stream>>>(Sf, F, F + R1, nullptr);
    gemm_s<<<dim3(32, 32), 256, 0, stream>>>(Sb, F, F + 3 * R1, nullptr);
    gemm_s<<<dim3(32, 32), 256, 0, stream>>>(Sf, F + R1, F + 2 * R1, F);
    gemm_s<<<dim3(32, 32), 256, 0, stream>>>(Sb, F + 3 * R1, F + 4 * R1, F);
  }
  proj_k<128, 640><<<dim3(32, 2, 32), 256, 0, stream>>>(Wg1t, F, bg1, G, 128, 0);
  candpack<<<4096, 256, 0, stream>>>(G, F, 128, 64);
  if (big) {
    gemm256<<<g256, 1024, 0, stream>>>(Sfb, F, F + R1, nullptr);
    gemm256<<<g256, 1024, 0, stream>>>(Sbb, F, F + 3 * R1, nullptr);
    gemm256<<<g256, 1024, 0, stream>>>(Sfb, F + R1, F + 2 * R1, F);
    gemm256<<<g256, 1024, 0, stream>>>(Sbb, F + 3 * R1, F + 4 * R1, F);
  } else {
    gemm_s<<<dim3(32, 32), 256, 0, stream>>>(Sf, F, F + R1, nullptr);
    gemm_s<<<dim3(32, 32), 256, 0, stream>>>(Sb, F, F + 3 * R1, nullptr);
    gemm_s<<<dim3(32, 32), 256, 0, stream>>>(Sf, F + R1, F + 2 * R1, F);
    gemm_s<<<dim3(32, 32), 256, 0, stream>>>(Sb, F + 3 * R1, F + 4 * R1, F);
  }
  proj_k<128, 640><<<dim3(32, 1, 32), 256, 0, stream>>>(Wc1t, F, bc1, G, 128, 1);
  hnew_k<<<dim3(64, 32), 256, 0, stream>>>(G, HID1, F, OUT_H1);

  predictk<<<512, 256, 0, stream>>>(OUT_H1, Wp, bp, OUT);
}